// Round 4
// baseline (15109.007 us; speedup 1.0000x reference)
//
#include <hip/hip_runtime.h>
#include <cstdint>

// ---------------------------------------------------------------------------
// LorentzMLA on MI355X (gfx950). R4: BISECT ROUND — pure fp32 VALU pipeline.
// No MFMA, no bf16, no global_load_lds, no d_out scratch. Correctness only.
// B=4 S=1024 DIM=2048 H=16 NOPE=128 ROPE=64 VSP=128 QK=192 KVR=512
// ---------------------------------------------------------------------------

#define DEV __device__ __forceinline__

static constexpr int S_ = 1024;

DEV float wred_sum(float v) {
  v += __shfl_xor(v, 1);  v += __shfl_xor(v, 2);  v += __shfl_xor(v, 4);
  v += __shfl_xor(v, 8);  v += __shfl_xor(v, 16); v += __shfl_xor(v, 32);
  return v;
}

// ---------------------------------------------------------------------------
// fp32 -> fp32 copy with zero padding. dst (rd x cd), src (rs x cs).
// ---------------------------------------------------------------------------
__global__ __launch_bounds__(256)
void pad_copy_f32(const float* __restrict__ src, float* __restrict__ dst,
                  int rs, int cs, int cd, int total) {
  int idx = blockIdx.x * 256 + threadIdx.x;
  if (idx >= total) return;
  int r = idx / cd, c = idx - r * cd;
  dst[idx] = (r < rs && c < cs) ? src[(size_t)r * cs + c] : 0.f;
}

// ---------------------------------------------------------------------------
// Naive tiled fp32 GEMM: out[m][n] = sum_k A[m][k]*W[n][k] + bias[n].
// A: M x K (M mult of 16), W: N x K (N mult of 16, rows >= grid range),
// K mult of 16. Stores n < nstore at row stride ldo.
// ---------------------------------------------------------------------------
__global__ __launch_bounds__(256)
void gemm_f32(const float* __restrict__ A, const float* __restrict__ W,
              const float* __restrict__ bias, float* __restrict__ out,
              int K, int ldo, int nstore) {
  __shared__ float As[16][17];
  __shared__ float Ws[16][17];
  const int tx = threadIdx.x, ty = threadIdx.y;
  const int bm = blockIdx.y * 16, bn = blockIdx.x * 16;
  float acc = 0.f;
  for (int k0 = 0; k0 < K; k0 += 16) {
    As[ty][tx] = A[(size_t)(bm + ty) * K + k0 + tx];
    Ws[ty][tx] = W[(size_t)(bn + ty) * K + k0 + tx];
    __syncthreads();
#pragma unroll
    for (int kk = 0; kk < 16; kk++) acc += As[ty][kk] * Ws[tx][kk];
    __syncthreads();
  }
  const int n = bn + tx;
  if (n < nstore) out[(size_t)(bm + ty) * ldo + n] = acc + bias[n];
}

// ---------------------------------------------------------------------------
// qpre (4096 x 3072) -> qhat (65536 x 192) + QT. One wave per (b,h,s) row.
// qhat row: [q_nope(128), rope(q_pe)(64)]; QT = sqrt(|row|^2 + 1).
// ---------------------------------------------------------------------------
__global__ __launch_bounds__(256)
void q_assemble_f32(const float* __restrict__ qpre, const float* __restrict__ fcos,
                    const float* __restrict__ fsin, float* __restrict__ qhat,
                    float* __restrict__ QT) {
  int row = blockIdx.x * 4 + (threadIdx.x >> 6);   // = bh*1024 + s
  int lane = threadIdx.x & 63;
  int b = row >> 14, h = (row >> 10) & 15, s = row & 1023;
  const float* src = qpre + (size_t)(b * 1024 + s) * 3072 + h * 192;
  float e0 = src[2 * lane], e1 = src[2 * lane + 1];
  float y1 = 0.f, y2 = 0.f;
  float sq = e0 * e0 + e1 * e1;
  if (lane < 32) {
    float x1 = src[128 + 2 * lane], x2 = src[128 + 2 * lane + 1];
    float c = fcos[s * 32 + lane], sn = fsin[s * 32 + lane];
    y1 = x1 * c - x2 * sn;
    y2 = x1 * sn + x2 * c;
    sq += x1 * x1 + x2 * x2;
  }
  sq = wred_sum(sq);
  float* dst = qhat + (size_t)row * 192;
  dst[2 * lane] = e0;
  dst[2 * lane + 1] = e1;
  if (lane < 32) { dst[128 + 2 * lane] = y1; dst[128 + 2 * lane + 1] = y2; }
  if (lane == 0) QT[row] = sqrtf(sq + 1.0f);
}

// ---------------------------------------------------------------------------
// kvfull (4096 x 576) -> kvn (4096 x 528: [t, sp512, 15 zeros]) + kpe (4096x64).
// ---------------------------------------------------------------------------
__global__ __launch_bounds__(256)
void kv_assemble1_f32(const float* __restrict__ kvfull, const float* __restrict__ wnorm,
                      const float* __restrict__ fcos, const float* __restrict__ fsin,
                      float* __restrict__ kvn, float* __restrict__ kpe) {
  int row = blockIdx.x * 4 + (threadIdx.x >> 6);   // b*1024 + s
  int lane = threadIdx.x & 63;
  int s = row & 1023;
  const float* src = kvfull + (size_t)row * 576;
  float v[8];
  float sq = 0.f;
#pragma unroll
  for (int i = 0; i < 8; i++) { v[i] = src[i * 64 + lane]; sq += v[i] * v[i]; }
  sq = wred_sum(sq);
  float rinv = rsqrtf(sq * (1.f / 512.f) + 1e-6f);
  float sq2 = 0.f;
#pragma unroll
  for (int i = 0; i < 8; i++) {
    v[i] = v[i] * rinv * wnorm[i * 64 + lane];
    sq2 += v[i] * v[i];
  }
  sq2 = wred_sum(sq2);
  float* dst = kvn + (size_t)row * 528;
#pragma unroll
  for (int i = 0; i < 8; i++) dst[1 + i * 64 + lane] = v[i];
  if (lane == 0) dst[0] = sqrtf(sq2 + 1.0f);
  if (lane < 15) dst[513 + lane] = 0.f;
  if (lane < 32) {
    float x1 = src[512 + 2 * lane], x2 = src[512 + 2 * lane + 1];
    float c = fcos[s * 32 + lane], sn = fsin[s * 32 + lane];
    kpe[(size_t)row * 64 + 2 * lane]     = x1 * c - x2 * sn;
    kpe[(size_t)row * 64 + 2 * lane + 1] = x1 * sn + x2 * c;
  }
}

// ---------------------------------------------------------------------------
// KT/VT from kv2 (4096 x 4096) + kpe. One wave per r = bh*1024 + s.
// KT[r] = sqrt(|k_nope|^2 + |kpe_roped|^2 + 1); VT[r] = sqrt(|v|^2 + 1).
// ---------------------------------------------------------------------------
__global__ __launch_bounds__(256)
void kt_vt_f32(const float* __restrict__ kv2, const float* __restrict__ kpe,
               float* __restrict__ KT, float* __restrict__ VT) {
  int r = blockIdx.x * 4 + (threadIdx.x >> 6);
  int lane = threadIdx.x & 63;
  int bh = r >> 10, s = r & 1023, b = bh >> 4, h = bh & 15;
  const float* src = kv2 + (size_t)(b * 1024 + s) * 4096 + h * 256;
  float e0 = src[2 * lane], e1 = src[2 * lane + 1];
  float sqk = e0 * e0 + e1 * e1;
  if (lane < 32) {
    float y1 = kpe[(size_t)(b * 1024 + s) * 64 + 2 * lane];
    float y2 = kpe[(size_t)(b * 1024 + s) * 64 + 2 * lane + 1];
    sqk += y1 * y1 + y2 * y2;
  }
  sqk = wred_sum(sqk);
  float v0 = src[128 + 2 * lane], v1 = src[128 + 2 * lane + 1];
  float sqv = wred_sum(v0 * v0 + v1 * v1);
  if (lane == 0) {
    KT[r] = sqrtf(sqk + 1.0f);
    VT[r] = sqrtf(sqv + 1.0f);
  }
}

// ---------------------------------------------------------------------------
// Naive fp32 attention + Lorentz normalize. One block per (bh, s).
// Reads kv2/kpe directly (no khat/vhat materialization).
// ---------------------------------------------------------------------------
__global__ __launch_bounds__(256)
void attn_f32(const float* __restrict__ qhat, const float* __restrict__ kv2,
              const float* __restrict__ kpe, const float* __restrict__ QT,
              const float* __restrict__ KT, const float* __restrict__ VT,
              float* __restrict__ cent) {
  __shared__ float qr_[192];
  __shared__ float sc[1024];
  __shared__ float red[256];
  __shared__ float av[129];
  const int tid = threadIdx.x;
  const int bh = blockIdx.y, b = bh >> 4, h = bh & 15;
  const int s = blockIdx.x;
  const float twoSig = 2.0f / sqrtf(193.0f);

  if (tid < 192) qr_[tid] = qhat[((size_t)bh * 1024 + s) * 192 + tid];
  __syncthreads();
  const float qt = QT[bh * 1024 + s];

  float lmax = -1e30f;
  for (int t = tid; t <= s; t += 256) {
    const float* kb = kv2 + (size_t)(b * 1024 + t) * 4096 + h * 256;
    const float* pb = kpe + (size_t)(b * 1024 + t) * 64;
    float acc = 0.f;
    for (int i = 0; i < 128; i++) acc += qr_[i] * kb[i];
    for (int i = 0; i < 64; i++)  acc += qr_[128 + i] * pb[i];
    float v = 2.f + twoSig * (acc - qt * KT[bh * 1024 + t]);
    sc[t] = v;
    lmax = fmaxf(lmax, v);
  }
  red[tid] = lmax;
  __syncthreads();
  for (int o = 128; o > 0; o >>= 1) {
    if (tid < o) red[tid] = fmaxf(red[tid], red[tid + o]);
    __syncthreads();
  }
  const float m = red[0];
  __syncthreads();

  float lsum = 0.f;
  for (int t = tid; t <= s; t += 256) {
    float p = __expf(sc[t] - m);
    sc[t] = p;
    lsum += p;
  }
  red[tid] = lsum;
  __syncthreads();
  for (int o = 128; o > 0; o >>= 1) {
    if (tid < o) red[tid] += red[tid + o];
    __syncthreads();
  }
  const float Linv = 1.0f / red[0];
  __syncthreads();

  if (tid < 129) {
    float a = 0.f;
    if (tid == 0) {
      for (int t = 0; t <= s; t++) a += sc[t] * VT[bh * 1024 + t];
    } else {
      const float* vb = kv2 + (size_t)b * 1024 * 4096 + h * 256 + 128 + (tid - 1);
      for (int t = 0; t <= s; t++) a += sc[t] * vb[(size_t)t * 4096];
    }
    float an = a * Linv;
    av[tid] = an;
    red[tid] = (tid >= 1) ? an * an : 0.f;
  } else {
    red[tid] = 0.f;
  }
  __syncthreads();
  for (int o = 128; o > 0; o >>= 1) {
    if (tid < o) red[tid] += red[tid + o];
    __syncthreads();
  }
  const float a0 = av[0];
  const float neg = a0 * a0 - red[0];
  const float rr = rsqrtf(fmaxf(fabsf(neg), 1e-8f));
  if (tid < 129)
    cent[((size_t)b * 1024 + s) * 2064 + h * 129 + tid] = av[tid] * rr;
}

// ---------------------------------------------------------------------------
__global__ __launch_bounds__(256)
void out_time(float* __restrict__ out) {
  int row = blockIdx.x * 4 + (threadIdx.x >> 6);
  int lane = threadIdx.x & 63;
  float* p = out + (size_t)row * 2048;
  float sq = 0.f;
#pragma unroll
  for (int i = 0; i < 32; i++) {
    int c = 1 + i * 64 + lane;
    if (c < 2048) { float v = p[c]; sq += v * v; }
  }
  sq = wred_sum(sq);
  if (lane == 0) p[0] = sqrtf(sq + 1.0f);
}

// ---------------------------------------------------------------------------
extern "C" void kernel_launch(void* const* d_in, const int* in_sizes, int n_in,
                              void* d_out, int out_size, void* d_ws, size_t ws_size,
                              hipStream_t stream) {
  const float* x      = (const float*)d_in[0];
  const float* fcos   = (const float*)d_in[1];
  const float* fsin   = (const float*)d_in[2];
  // d_in[3] = mask (causal, analytic)
  const float* wq_w   = (const float*)d_in[4];
  const float* wq_b   = (const float*)d_in[5];
  const float* wkva_w = (const float*)d_in[6];
  const float* wkva_b = (const float*)d_in[7];
  const float* kvnw   = (const float*)d_in[8];
  const float* wkvb_w = (const float*)d_in[9];
  const float* wkvb_b = (const float*)d_in[10];
  const float* wo_w   = (const float*)d_in[11];
  const float* wo_b   = (const float*)d_in[12];

  // ---- workspace (~170.3 MB), lifetime-aliased ----
  char* ws = (char*)d_ws;
  const size_t off_A = 0;                         // kv2: 4096*4096*4 = 67,108,864
  const size_t off_B = 67108864;                  // qhat + QT/KT/VT + kpe
  const size_t off_C = off_B + 52428800;          // qpre | kvfull/kvn/W2f | cent/W3f

  float* kv2    = (float*)(ws + off_A);
  float* qhat   = (float*)(ws + off_B);                    // 50,331,648
  float* QT     = (float*)(ws + off_B + 50331648);         // 262,144
  float* KT     = (float*)(ws + off_B + 50593792);         // 262,144
  float* VT     = (float*)(ws + off_B + 50855936);         // 262,144
  float* kpe    = (float*)(ws + off_B + 51118080);         // 1,048,576
  float* qpre   = (float*)(ws + off_C);                    // 50,331,648
  float* kvfull = (float*)(ws + off_C);                    // 9,437,184
  float* kvn    = (float*)(ws + off_C +  9437184);         // 8,650,752
  float* W2f    = (float*)(ws + off_C + 18087936);         // 8,650,752
  float* cent   = (float*)(ws + off_C);                    // 33,816,576
  float* W3f    = (float*)(ws + off_C + 33816576);         // 16,908,288

  int t;
  // 1. qpre = x @ wq^T   (4096 x 3072, K=2048)
  gemm_f32<<<dim3(192, 256), dim3(16, 16), 0, stream>>>(
      x, wq_w, wq_b, qpre, 2048, 3072, 3072);
  // 2. q assembly
  q_assemble_f32<<<16384, 256, 0, stream>>>(qpre, fcos, fsin, qhat, QT);
  // 3. kvfull = x @ wkva^T   (4096 x 576, K=2048)  [qpre dead]
  gemm_f32<<<dim3(36, 256), dim3(16, 16), 0, stream>>>(
      x, wkva_w, wkva_b, kvfull, 2048, 576, 576);
  // 4. RMSNorm + project + rope(k_pe)
  kv_assemble1_f32<<<1024, 256, 0, stream>>>(kvfull, kvnw, fcos, fsin, kvn, kpe);
  // 5. W2f = wkvb padded (4096 x 513) -> (4096 x 528)
  t = 4096 * 528;
  pad_copy_f32<<<(t + 255) / 256, 256, 0, stream>>>(wkvb_w, W2f, 4096, 513, 528, t);
  // 6. kv2 = kvn @ wkvb^T   (4096 x 4096, K=528)
  gemm_f32<<<dim3(256, 256), dim3(16, 16), 0, stream>>>(
      kvn, W2f, wkvb_b, kv2, 528, 4096, 4096);
  // 7. KT / VT
  kt_vt_f32<<<16384, 256, 0, stream>>>(kv2, kpe, KT, VT);
  // 8. attention -> cent  [kvfull/kvn/W2f dead]
  attn_f32<<<dim3(1024, 64), 256, 0, stream>>>(qhat, kv2, kpe, QT, KT, VT, cent);
  // 9. W3f = wo padded (2047 x 2064) -> (2048 x 2064)
  t = 2048 * 2064;
  pad_copy_f32<<<(t + 255) / 256, 256, 0, stream>>>(wo_w, W3f, 2047, 2064, 2064, t);
  // 10. y = cent @ wo^T -> d_out cols 1..2047  (4096 x 2048, K=2064)
  gemm_f32<<<dim3(128, 256), dim3(16, 16), 0, stream>>>(
      cent, W3f, wo_b, (float*)d_out + 1, 2064, 2048, 2047);
  // 11. time component
  out_time<<<1024, 256, 0, stream>>>((float*)d_out);
}

// Round 5
// 8359.309 us; speedup vs baseline: 1.8074x; 1.8074x over previous
//
#include <hip/hip_runtime.h>
#include <cstdint>

// ---------------------------------------------------------------------------
// LorentzMLA on MI355X (gfx950). R5: R4 fp32 pipeline + MFMA bf16 GEMMs
// (fp32 outputs). Assemblies/attention byte-identical to passing R4 except
// bf16 stores for kvn and cent (MFMA A-operands).
// ---------------------------------------------------------------------------

typedef unsigned short u16;
typedef __bf16 bf16x8 __attribute__((ext_vector_type(8)));
typedef float f32x4 __attribute__((ext_vector_type(4)));

#define DEV __device__ __forceinline__

DEV u16 f2bf(float f) {
  unsigned u = __builtin_bit_cast(unsigned, f);
  u = u + 0x7fffu + ((u >> 16) & 1u);
  return (u16)(u >> 16);
}

DEV void async16(void* lds, const void* g) {
  __builtin_amdgcn_global_load_lds(
      (__attribute__((address_space(1))) void*)(uintptr_t)g,
      (__attribute__((address_space(3))) void*)lds, 16, 0, 0);
}

DEV float wred_sum(float v) {
  v += __shfl_xor(v, 1);  v += __shfl_xor(v, 2);  v += __shfl_xor(v, 4);
  v += __shfl_xor(v, 8);  v += __shfl_xor(v, 16); v += __shfl_xor(v, 32);
  return v;
}

// ---------------------------------------------------------------------------
// fp32 -> bf16 with zero padding. dst (rd x cd), src (rs x cs).
// ---------------------------------------------------------------------------
__global__ __launch_bounds__(256)
void pad_convert(const float* __restrict__ src, u16* __restrict__ dst,
                 int rs, int cs, int cd, int total) {
  int idx = blockIdx.x * 256 + threadIdx.x;
  if (idx >= total) return;
  int r = idx / cd, c = idx - r * cd;
  float v = (r < rs && c < cs) ? src[(size_t)r * cs + c] : 0.f;
  dst[idx] = f2bf(v);
}

// ---------------------------------------------------------------------------
// out[m][n] = sum_k A[m][k]*W[n][k] + bias[n].  A: MxK bf16, W: NxK bf16.
// 128x128 tile, BK=32, 16x16x32 MFMA, global_load_lds(16B) staging. fp32 out.
// ---------------------------------------------------------------------------
__global__ __launch_bounds__(256)
void gemm_bt(const u16* __restrict__ A, const u16* __restrict__ W,
             const float* __restrict__ bias, float* __restrict__ outF,
             int K, int ldo, int nstore) {
  __shared__ __align__(16) u16 As[128 * 32];
  __shared__ __align__(16) u16 Bs[128 * 32];
  const int tid = threadIdx.x;
  const int w = tid >> 6, lane = tid & 63;
  const int quad = lane >> 4, l16 = lane & 15;
  const int bm = blockIdx.y * 128, bn = blockIdx.x * 128;
  const int wm = (w & 1) * 64, wn = (w >> 1) * 64;
  const int sr = lane >> 2;
  const int sc = (lane & 3) * 8;

  f32x4 acc[4][4];
#pragma unroll
  for (int i = 0; i < 4; i++)
#pragma unroll
    for (int j = 0; j < 4; j++) acc[i][j] = (f32x4){0.f, 0.f, 0.f, 0.f};

  const u16* Ab = A + (size_t)bm * K;
  const u16* Wb = W + (size_t)bn * K;

  for (int k0 = 0; k0 < K; k0 += 32) {
    __syncthreads();
#pragma unroll
    for (int i = 0; i < 2; ++i) {
      int rr = w * 32 + i * 16;
      async16((char*)&As[rr * 32] + (size_t)lane * 16,
              Ab + (size_t)(rr + sr) * K + k0 + sc);
      async16((char*)&Bs[rr * 32] + (size_t)lane * 16,
              Wb + (size_t)(rr + sr) * K + k0 + sc);
    }
    __syncthreads();
    bf16x8 aF[4], bF[4];
#pragma unroll
    for (int i = 0; i < 4; i++)
      aF[i] = *(const bf16x8*)&As[(wm + i * 16 + l16) * 32 + quad * 8];
#pragma unroll
    for (int i = 0; i < 4; i++)
      bF[i] = *(const bf16x8*)&Bs[(wn + i * 16 + l16) * 32 + quad * 8];
#pragma unroll
    for (int im = 0; im < 4; im++)
#pragma unroll
      for (int in = 0; in < 4; in++)
        acc[im][in] = __builtin_amdgcn_mfma_f32_16x16x32_bf16(
            aF[im], bF[in], acc[im][in], 0, 0, 0);
  }

#pragma unroll
  for (int im = 0; im < 4; im++) {
#pragma unroll
    for (int in = 0; in < 4; in++) {
      int gn = bn + wn + in * 16 + l16;
      if (gn >= nstore) continue;
      float bv = bias[gn];
#pragma unroll
      for (int j = 0; j < 4; j++) {
        int gm = bm + wm + im * 16 + quad * 4 + j;
        outF[(size_t)gm * ldo + gn] = acc[im][in][j] + bv;
      }
    }
  }
}

// ---------------------------------------------------------------------------
// qpre (4096 x 3072 f32) -> qhat (65536 x 192 f32) + QT. (R4, unchanged)
// ---------------------------------------------------------------------------
__global__ __launch_bounds__(256)
void q_assemble_f32(const float* __restrict__ qpre, const float* __restrict__ fcos,
                    const float* __restrict__ fsin, float* __restrict__ qhat,
                    float* __restrict__ QT) {
  int row = blockIdx.x * 4 + (threadIdx.x >> 6);   // = bh*1024 + s
  int lane = threadIdx.x & 63;
  int b = row >> 14, h = (row >> 10) & 15, s = row & 1023;
  const float* src = qpre + (size_t)(b * 1024 + s) * 3072 + h * 192;
  float e0 = src[2 * lane], e1 = src[2 * lane + 1];
  float y1 = 0.f, y2 = 0.f;
  float sq = e0 * e0 + e1 * e1;
  if (lane < 32) {
    float x1 = src[128 + 2 * lane], x2 = src[128 + 2 * lane + 1];
    float c = fcos[s * 32 + lane], sn = fsin[s * 32 + lane];
    y1 = x1 * c - x2 * sn;
    y2 = x1 * sn + x2 * c;
    sq += x1 * x1 + x2 * x2;
  }
  sq = wred_sum(sq);
  float* dst = qhat + (size_t)row * 192;
  dst[2 * lane] = e0;
  dst[2 * lane + 1] = e1;
  if (lane < 32) { dst[128 + 2 * lane] = y1; dst[128 + 2 * lane + 1] = y2; }
  if (lane == 0) QT[row] = sqrtf(sq + 1.0f);
}

// ---------------------------------------------------------------------------
// kvfull (4096 x 576 f32) -> kvnb (4096 x 544 bf16: [t, sp512, 31 zeros])
// + kpe (4096 x 64 f32).  (R4 logic; bf16 store for MFMA gemm4.)
// ---------------------------------------------------------------------------
__global__ __launch_bounds__(256)
void kv_assemble1_f32(const float* __restrict__ kvfull, const float* __restrict__ wnorm,
                      const float* __restrict__ fcos, const float* __restrict__ fsin,
                      u16* __restrict__ kvnb, float* __restrict__ kpe) {
  int row = blockIdx.x * 4 + (threadIdx.x >> 6);   // b*1024 + s
  int lane = threadIdx.x & 63;
  int s = row & 1023;
  const float* src = kvfull + (size_t)row * 576;
  float v[8];
  float sq = 0.f;
#pragma unroll
  for (int i = 0; i < 8; i++) { v[i] = src[i * 64 + lane]; sq += v[i] * v[i]; }
  sq = wred_sum(sq);
  float rinv = rsqrtf(sq * (1.f / 512.f) + 1e-6f);
  float sq2 = 0.f;
#pragma unroll
  for (int i = 0; i < 8; i++) {
    v[i] = v[i] * rinv * wnorm[i * 64 + lane];
    sq2 += v[i] * v[i];
  }
  sq2 = wred_sum(sq2);
  u16* dst = kvnb + (size_t)row * 544;
#pragma unroll
  for (int i = 0; i < 8; i++) dst[1 + i * 64 + lane] = f2bf(v[i]);
  if (lane == 0) dst[0] = f2bf(sqrtf(sq2 + 1.0f));
  if (lane < 31) dst[513 + lane] = 0;
  if (lane < 32) {
    float x1 = src[512 + 2 * lane], x2 = src[512 + 2 * lane + 1];
    float c = fcos[s * 32 + lane], sn = fsin[s * 32 + lane];
    kpe[(size_t)row * 64 + 2 * lane]     = x1 * c - x2 * sn;
    kpe[(size_t)row * 64 + 2 * lane + 1] = x1 * sn + x2 * c;
  }
}

// ---------------------------------------------------------------------------
// KT/VT from kv2 (4096 x 4096 f32) + kpe. (R4, unchanged)
// ---------------------------------------------------------------------------
__global__ __launch_bounds__(256)
void kt_vt_f32(const float* __restrict__ kv2, const float* __restrict__ kpe,
               float* __restrict__ KT, float* __restrict__ VT) {
  int r = blockIdx.x * 4 + (threadIdx.x >> 6);
  int lane = threadIdx.x & 63;
  int bh = r >> 10, s = r & 1023, b = bh >> 4, h = bh & 15;
  const float* src = kv2 + (size_t)(b * 1024 + s) * 4096 + h * 256;
  float e0 = src[2 * lane], e1 = src[2 * lane + 1];
  float sqk = e0 * e0 + e1 * e1;
  if (lane < 32) {
    float y1 = kpe[(size_t)(b * 1024 + s) * 64 + 2 * lane];
    float y2 = kpe[(size_t)(b * 1024 + s) * 64 + 2 * lane + 1];
    sqk += y1 * y1 + y2 * y2;
  }
  sqk = wred_sum(sqk);
  float v0 = src[128 + 2 * lane], v1 = src[128 + 2 * lane + 1];
  float sqv = wred_sum(v0 * v0 + v1 * v1);
  if (lane == 0) {
    KT[r] = sqrtf(sqk + 1.0f);
    VT[r] = sqrtf(sqv + 1.0f);
  }
}

// ---------------------------------------------------------------------------
// Naive fp32 attention + Lorentz normalize. (R4 logic; bf16 cent store,
// 2080-wide for MFMA gemm5.)
// ---------------------------------------------------------------------------
__global__ __launch_bounds__(256)
void attn_f32(const float* __restrict__ qhat, const float* __restrict__ kv2,
              const float* __restrict__ kpe, const float* __restrict__ QT,
              const float* __restrict__ KT, const float* __restrict__ VT,
              u16* __restrict__ centb) {
  __shared__ float qr_[192];
  __shared__ float sc[1024];
  __shared__ float red[256];
  __shared__ float av[129];
  const int tid = threadIdx.x;
  const int bh = blockIdx.y, b = bh >> 4, h = bh & 15;
  const int s = blockIdx.x;
  const float twoSig = 2.0f / sqrtf(193.0f);

  if (tid < 192) qr_[tid] = qhat[((size_t)bh * 1024 + s) * 192 + tid];
  __syncthreads();
  const float qt = QT[bh * 1024 + s];

  float lmax = -1e30f;
  for (int t = tid; t <= s; t += 256) {
    const float* kb = kv2 + (size_t)(b * 1024 + t) * 4096 + h * 256;
    const float* pb = kpe + (size_t)(b * 1024 + t) * 64;
    float acc = 0.f;
    for (int i = 0; i < 128; i++) acc += qr_[i] * kb[i];
    for (int i = 0; i < 64; i++)  acc += qr_[128 + i] * pb[i];
    float v = 2.f + twoSig * (acc - qt * KT[bh * 1024 + t]);
    sc[t] = v;
    lmax = fmaxf(lmax, v);
  }
  red[tid] = lmax;
  __syncthreads();
  for (int o = 128; o > 0; o >>= 1) {
    if (tid < o) red[tid] = fmaxf(red[tid], red[tid + o]);
    __syncthreads();
  }
  const float m = red[0];
  __syncthreads();

  float lsum = 0.f;
  for (int t = tid; t <= s; t += 256) {
    float p = __expf(sc[t] - m);
    sc[t] = p;
    lsum += p;
  }
  red[tid] = lsum;
  __syncthreads();
  for (int o = 128; o > 0; o >>= 1) {
    if (tid < o) red[tid] += red[tid + o];
    __syncthreads();
  }
  const float Linv = 1.0f / red[0];
  __syncthreads();

  if (tid < 129) {
    float a = 0.f;
    if (tid == 0) {
      for (int t = 0; t <= s; t++) a += sc[t] * VT[bh * 1024 + t];
    } else {
      const float* vb = kv2 + (size_t)b * 1024 * 4096 + h * 256 + 128 + (tid - 1);
      for (int t = 0; t <= s; t++) a += sc[t] * vb[(size_t)t * 4096];
    }
    float an = a * Linv;
    av[tid] = an;
    red[tid] = (tid >= 1) ? an * an : 0.f;
  } else {
    red[tid] = 0.f;
  }
  __syncthreads();
  for (int o = 128; o > 0; o >>= 1) {
    if (tid < o) red[tid] += red[tid + o];
    __syncthreads();
  }
  const float a0 = av[0];
  const float neg = a0 * a0 - red[0];
  const float rr = rsqrtf(fmaxf(fabsf(neg), 1e-8f));
  if (tid < 129)
    centb[((size_t)b * 1024 + s) * 2080 + h * 129 + tid] = f2bf(av[tid] * rr);
}

// ---------------------------------------------------------------------------
__global__ __launch_bounds__(256)
void out_time(float* __restrict__ out) {
  int row = blockIdx.x * 4 + (threadIdx.x >> 6);
  int lane = threadIdx.x & 63;
  float* p = out + (size_t)row * 2048;
  float sq = 0.f;
#pragma unroll
  for (int i = 0; i < 32; i++) {
    int c = 1 + i * 64 + lane;
    if (c < 2048) { float v = p[c]; sq += v * v; }
  }
  sq = wred_sum(sq);
  if (lane == 0) p[0] = sqrtf(sq + 1.0f);
}

// ---------------------------------------------------------------------------
extern "C" void kernel_launch(void* const* d_in, const int* in_sizes, int n_in,
                              void* d_out, int out_size, void* d_ws, size_t ws_size,
                              hipStream_t stream) {
  const float* x      = (const float*)d_in[0];
  const float* fcos   = (const float*)d_in[1];
  const float* fsin   = (const float*)d_in[2];
  // d_in[3] = mask (causal, analytic)
  const float* wq_w   = (const float*)d_in[4];
  const float* wq_b   = (const float*)d_in[5];
  const float* wkva_w = (const float*)d_in[6];
  const float* wkva_b = (const float*)d_in[7];
  const float* kvnw   = (const float*)d_in[8];
  const float* wkvb_w = (const float*)d_in[9];
  const float* wkvb_b = (const float*)d_in[10];
  const float* wo_w   = (const float*)d_in[11];
  const float* wo_b   = (const float*)d_in[12];

  // ---- workspace (~169.9 MB), lifetime-aliased ----
  char* ws = (char*)d_ws;
  float* qhat   = (float*)(ws);                            // 50,331,648
  float* QT     = (float*)(ws + 50331648);                 // 262,144
  float* KT     = (float*)(ws + 50593792);                 // 262,144
  float* VT     = (float*)(ws + 50855936);                 // 262,144
  float* kpe    = (float*)(ws + 51118080);                 // 1,048,576
  const size_t offA = 52166656;   // qpre f32 (50.3M) -> kv2 f32 (67.1M)
  float* qpre   = (float*)(ws + offA);
  float* kv2    = (float*)(ws + offA);
  const size_t offB = offA + 67108864;  // xb bf16 (16.8M) -> centb bf16 (17.0M)
  u16*   xb     = (u16*)  (ws + offB);
  u16*   centb  = (u16*)  (ws + offB);
  const size_t offC = offB + 17039360;  // W0b (12.6M) -> W3b (8.5M)
  u16*   W0b    = (u16*)  (ws + offC);
  u16*   W3b    = (u16*)  (ws + offC);
  const size_t offD = offC + 12582912;  // small weights + kvfull
  u16*   W1b    = (u16*)  (ws + offD);                     // 2,621,440
  u16*   W2b    = (u16*)  (ws + offD + 2621440);           // 4,456,448
  u16*   kvnb   = (u16*)  (ws + offD + 7077888);           // 4,456,448
  float* kvfull = (float*)(ws + offD + 11534336);          // 9,437,184

  int t;
  // 1. convert x / wq
  t = 4096 * 2048;
  pad_convert<<<(t + 255) / 256, 256, 0, stream>>>(x, xb, 4096, 2048, 2048, t);
  t = 3072 * 2048;
  pad_convert<<<(t + 255) / 256, 256, 0, stream>>>(wq_w, W0b, 3072, 2048, 2048, t);
  // 2. qpre = x @ wq^T (fp32 out)
  gemm_bt<<<dim3(24, 32), 256, 0, stream>>>(xb, W0b, wq_b, qpre, 2048, 3072, 3072);
  // 3. q assembly (fp32, unchanged)
  q_assemble_f32<<<16384, 256, 0, stream>>>(qpre, fcos, fsin, qhat, QT);
  // 4. kvfull = x @ wkva^T (fp32 out)
  t = 640 * 2048;
  pad_convert<<<(t + 255) / 256, 256, 0, stream>>>(wkva_w, W1b, 576, 2048, 2048, t);
  gemm_bt<<<dim3(5, 32), 256, 0, stream>>>(xb, W1b, wkva_b, kvfull, 2048, 576, 576);
  // 5. RMSNorm + project + rope(k_pe); kvn stored bf16
  kv_assemble1_f32<<<1024, 256, 0, stream>>>(kvfull, kvnw, fcos, fsin, kvnb, kpe);
  // 6. kv2 = kvn @ wkvb^T (fp32 out; overwrites qpre region — qpre dead)
  t = 4096 * 544;
  pad_convert<<<(t + 255) / 256, 256, 0, stream>>>(wkvb_w, W2b, 4096, 513, 544, t);
  gemm_bt<<<dim3(32, 32), 256, 0, stream>>>(kvnb, W2b, wkvb_b, kv2, 544, 4096, 4096);
  // 7. KT / VT (fp32, unchanged)
  kt_vt_f32<<<16384, 256, 0, stream>>>(kv2, kpe, KT, VT);
  // 8. attention -> centb bf16 (overwrites xb — dead)
  attn_f32<<<dim3(1024, 64), 256, 0, stream>>>(qhat, kv2, kpe, QT, KT, VT, centb);
  // 9. y = cent @ wo^T -> d_out cols 1..2047 (fp32)
  t = 2048 * 2080;
  pad_convert<<<(t + 255) / 256, 256, 0, stream>>>(wo_w, W3b, 2047, 2064, 2080, t);
  gemm_bt<<<dim3(16, 32), 256, 0, stream>>>(centb, W3b, wo_b, (float*)d_out + 1,
                                            2080, 2048, 2047);
  // 10. time component
  out_time<<<1024, 256, 0, stream>>>((float*)d_out);
}